// Round 11
// baseline (379.833 us; speedup 1.0000x reference)
//
#include <hip/hip_runtime.h>
#include <hip/hip_bf16.h>
#include <stdint.h>

typedef __attribute__((ext_vector_type(8))) short short8;
typedef __attribute__((ext_vector_type(4))) float f32x4;

#define WPP_BYTES 14155776ull   // 64hw*27tap*64co*64ci*2B (first in ws)
#define XPP_BYTES 66355200ull   // 8rh*8cw*2b*15rho*15cwo*18d*64ci*2B

__device__ __forceinline__ void gl2lds16(const void* g, void* l) {
    __builtin_amdgcn_global_load_lds(
        (const __attribute__((address_space(1))) unsigned int*)g,
        (__attribute__((address_space(3))) unsigned int*)l, 16, 0, 0);
}

// ---------------- prep: fused bzero + xform_x + xform_w (3 roles) ----------
// bid < 448: xform_x — X (f32) -> X''' (bf16 space-to-depth, d-innermost),
//   X'''[rh][cw][b][rho15][cwo15][d18][ci64]; src d at d+1, rho/cwo at +1.
// bid in [448,512): bzero — zero X''' halo (rho=0 | cwo=0 | d in {0,17}).
// bid >= 512: xform_w — W (f32) -> W''[hw][tap][co64][ci-chunks] (bf16).
__global__ __launch_bounds__(512)
void prep(const float* __restrict__ xin, const float* __restrict__ wt,
          __hip_bfloat16* __restrict__ xpp, __hip_bfloat16* __restrict__ wpp) {
    extern __shared__ char smc[];
    const int bid = blockIdx.x;
    const int tid = threadIdx.x;
    if (bid < 448) {
        __hip_bfloat16* Xl = (__hip_bfloat16*)smc;   // [r8][c112][ci64] swz
        const int rho = bid % 14, d = (bid / 14) % 16, b = bid / 224;
        for (int f = tid; f < 64 * 8 * 28; f += 512) {
            int ci = f / 224, rem = f % 224;
            int r = rem / 28, c4 = (rem % 28) * 4;
            const float4 v = *(const float4*)&xin[
                ((((size_t)b * 64 + ci) * 16 + d) * 112 + (rho * 8 + r)) * 112 + c4];
            const float vv[4] = {v.x, v.y, v.z, v.w};
#pragma unroll
            for (int u = 0; u < 4; ++u) {
                int c = c4 + u;
                Xl[(r * 112 + c) * 64 + (ci ^ ((c & 7) << 3))] = __float2bfloat16(vv[u]);
            }
        }
        __syncthreads();
        for (int f = tid; f < 896 * 8; f += 512) {
            int pos = f >> 3, j = f & 7;
            int r = pos / 112, c = pos % 112;
            int cw = c & 7, cwo = c >> 3;
            uint4 v = *(const uint4*)&Xl[pos * 64 + ((j * 8) ^ ((c & 7) << 3))];
            size_t dst = (((((size_t)(r * 8 + cw) * 2 + b) * 15 + (rho + 1)) * 15
                           + (cwo + 1)) * 18 + (d + 1)) * 64 + j * 8;
            *(uint4*)(xpp + dst) = v;
        }
    } else if (bid < 512) {
        uint4* xp4 = (uint4*)xpp;
        const uint4 z = {0u, 0u, 0u, 0u};
        const int total = 935936;
        for (int idx = (bid - 448) * 512 + tid; idx < total; idx += 64 * 512) {
            int u;
            if (idx < 276480) {
                int slab = idx / 2160, off = idx % 2160;
                u = slab * 32400 + off;
            } else if (idx < 534528) {
                int k = idx - 276480;
                int run = k / 144, off = k % 144;
                int slab = run / 14, rho = run % 14 + 1;
                u = slab * 32400 + rho * 2160 + off;
            } else {
                int k = idx - 534528;
                int run = k / 8, off = k % 8;
                int slab = run / 392, r2 = run % 392;
                int rho = r2 / 28 + 1, r3 = r2 % 28;
                int cwo = r3 / 2 + 1, d = (r3 & 1) * 17;
                u = slab * 32400 + rho * 2160 + cwo * 144 + d * 8 + off;
            }
            xp4[u] = z;
        }
    } else {
        __hip_bfloat16* lw = (__hip_bfloat16*)smc;   // [co8][k27][ci64 pad72]
        const int bb = bid - 512;
        const int hw = bb >> 3, cc = bb & 7;
        for (int f = tid; f < 8 * 64 * 27; f += 512) {
            int k = f % 27, ci = (f / 27) % 64, co = f / (27 * 64);
            float v = wt[(size_t)hw * 110592 + (size_t)(cc * 8 + co) * 1728 + ci * 27 + k];
            lw[(co * 27 + k) * 72 + ci] = __float2bfloat16(v);
        }
        __syncthreads();
        for (int f = tid; f < 27 * 8 * 8; f += 512) {
            int cic = f % 8, co = (f / 8) % 8, k = f / 64;
            uint4 v = *(const uint4*)&lw[(co * 27 + k) * 72 + cic * 8];
            size_t dst = (((size_t)hw * 27 + k) * 64 + (cc * 8 + co)) * 64 + cic * 8;
            *(uint4*)(wpp + dst) = v;
        }
    }
}

// ---------------- GEMM: per (h,w,b,mc): [224m x 64co], m=(wo14,t16) --------
// r10 geometry/offsets/epilogue (verified). Changes: B in REGISTERS (12
// short8 per (kh,kw)-pair, direct from L2-resident W'' slice, no-XOR chunk
// map = r10's LDS result composed with its inverse swizzle); LDS = A-only
// 2 x 16384 B => 4 blocks/CU (16 waves, 4/SIMD) — the untested TLP x lean-
// bytes cell. launch_bounds(256,4) pins VGPR <= 128 (acc 56 + bfr 48 + ~20).
__global__ __launch_bounds__(256, 4)
void patgemm(const __hip_bfloat16* __restrict__ xpp,
             const char* __restrict__ wppc,
             const float* __restrict__ bs,
             float* __restrict__ out) {
    __shared__ uint4 smemv[2048];           // 32768 B: A bufs 2 x 16384
    char* smem = (char*)smemv;
    const char* xppc = (const char*)xpp;
    const int bid = blockIdx.x;
    const int h = bid & 7, w = (bid >> 3) & 7, b = (bid >> 6) & 1, mc = bid >> 7;
    const int hw = h * 8 + w;
    const int tid = threadIdx.x, wv = tid >> 6;
    const int lane = tid & 63, col = lane & 15, quad = lane >> 4;
    const int mg = wv >> 1, ng = wv & 1;

    // A staging: slot u -> (wo=u/72, d=(u%72)>>2, q'=u&3); src q = q'^((d>>1)&3)
    uint32_t aoff[4];
#pragma unroll
    for (int i = 0; i < 4; ++i) {
        int u = tid + i * 256; if (u > 1007) u = 1007;   // src clamp only
        int wo = u / 72, rem = u - wo * 72;
        int d = rem >> 2, qp = rem & 3, q = qp ^ ((d >> 1) & 3);
        aoff[i] = (uint32_t)(wo * 2304 + d * 128 + q * 16);
    }
    // A read: row d = col+kd (64B rows), chunk quad^((d>>1)&3) [r10: 0-conflict]
    uint32_t rofs[3];
#pragma unroll
    for (int kd = 0; kd < 3; ++kd) {
        int d = col + kd;
        rofs[kd] = (uint32_t)(d * 64 + ((quad ^ ((d >> 1) & 3)) << 4));
    }
    // B direct-load base: chunk = hf*4+quad of row co (verified map)
    const char* wbase = wppc + (size_t)hw * 221184;
    const uint32_t bbase = (uint32_t)((ng * 32 + col) * 128 + quad * 16);

    f32x4 acc[7][2];
#pragma unroll
    for (int j = 0; j < 7; ++j)
#pragma unroll
        for (int n = 0; n < 2; ++n) acc[j][n] = (f32x4){0.f, 0.f, 0.f, 0.f};

    auto lineBase = [&](int p) -> const char* {
        const int kh = (p >= 6) ? 2 : (p >= 3 ? 1 : 0);
        const int kw = p - 3 * kh;
        const int r0 = h + kh - 7, c0 = w + kw - 7;
        return xppc + (size_t)(((((r0 & 7) * 8 + (c0 & 7)) * 2 + b) * 15
                    + ((r0 >> 3) + 1 + mc)) * 15 + ((c0 >> 3) + 1)) * 2304;
    };
    auto STGA = [&](const char* lb, int hf, int buf) {
#pragma unroll
        for (int i = 0; i < 4; ++i)
            gl2lds16(lb + aoff[i] + hf * 64,
                     smem + buf * 16384 + (tid + i * 256) * 16);
    };

    short8 bfr[12];

    // prologue: A(p=0,hf0) -> buf0
    const char* lb = lineBase(0);
    STGA(lb, 0, 0);
    __syncthreads();

#pragma unroll 1
    for (int p = 0; p < 9; ++p) {
        // B regs for pair p: taps {p, p+9, p+18}
#pragma unroll
        for (int kd = 0; kd < 3; ++kd)
#pragma unroll
            for (int hf = 0; hf < 2; ++hf)
#pragma unroll
                for (int n = 0; n < 2; ++n)
                    bfr[kd * 4 + hf * 2 + n] = *(const short8*)(
                        wbase + (size_t)(p + 9 * kd) * 8192 + bbase
                        + n * 2048 + hf * 64);
        STGA(lb, 1, 1);                       // A(p,hf1) -> buf1
        // ---- hf=0 compute from buf0 (compiler waits bfr via counted vmcnt)
#pragma unroll
        for (int kd = 0; kd < 3; ++kd) {
#pragma unroll
            for (int j = 0; j < 7; ++j) {
                short8 af = *(const short8*)(smem + (mg * 7 + j) * 1152 + rofs[kd]);
                acc[j][0] = __builtin_amdgcn_mfma_f32_16x16x32_bf16(af, bfr[kd * 4 + 0], acc[j][0], 0, 0, 0);
                acc[j][1] = __builtin_amdgcn_mfma_f32_16x16x32_bf16(af, bfr[kd * 4 + 1], acc[j][1], 0, 0, 0);
            }
        }
        __syncthreads();                      // drains buf1 writes
        if (p < 8) { lb = lineBase(p + 1); STGA(lb, 0, 0); }  // A(p+1,hf0)
        // ---- hf=1 compute from buf1
#pragma unroll
        for (int kd = 0; kd < 3; ++kd) {
#pragma unroll
            for (int j = 0; j < 7; ++j) {
                short8 af = *(const short8*)(smem + 16384 + (mg * 7 + j) * 1152 + rofs[kd]);
                acc[j][0] = __builtin_amdgcn_mfma_f32_16x16x32_bf16(af, bfr[kd * 4 + 2], acc[j][0], 0, 0, 0);
                acc[j][1] = __builtin_amdgcn_mfma_f32_16x16x32_bf16(af, bfr[kd * 4 + 3], acc[j][1], 0, 0, 0);
            }
        }
        __syncthreads();                      // drains buf0 writes
    }

    // epilogue (r10-verified): co=(ng*2+n)*16+col, t=quad*4+jj, wo=mg*7+j
    const float* bsl = bs + hw * 64;
    const int y = 8 * mc + h;
#pragma unroll
    for (int j = 0; j < 7; ++j) {
        const int x = 8 * (mg * 7 + j) + w;
#pragma unroll
        for (int n = 0; n < 2; ++n) {
            const int co = (ng * 2 + n) * 16 + col;
            const float bv = bsl[co];
#pragma unroll
            for (int jj = 0; jj < 4; ++jj) {
                const int t = quad * 4 + jj;
                out[((((size_t)b * 64 + co) * 16 + t) * 112 + y) * 112 + x]
                    = acc[j][n][jj] + bv;
            }
        }
    }
}

// ---------------- fallback: round-1 fp32 kernel (used if ws too small) -----
#define XL_ROWSTRIDE 116
#define WL_WSTRIDE (17*27)

__global__ __launch_bounds__(256, 3)
void patconv3d_fp32(const float* __restrict__ xin,
                    const float* __restrict__ wt,
                    const float* __restrict__ bs,
                    float* __restrict__ out) {
    __shared__ float Xl[3*3*7*XL_ROWSTRIDE];
    __shared__ float Wl[8*WL_WSTRIDE];
    const int bid = blockIdx.x;
    const int ct = bid & 3, hb = (bid >> 2) & 1, h = (bid >> 3) & 7;
    const int t = (bid >> 6) & 15, b = (bid >> 10) & 1;
    const int tid = threadIdx.x;
    const int xl = tid & 127, cg = tid >> 7;
    const int xr = (xl < 112) ? xl : 111;
    const int wq = xl & 7;
    float acc[8][7];
#pragma unroll
    for (int c = 0; c < 8; ++c)
#pragma unroll
        for (int ho = 0; ho < 7; ++ho) acc[c][ho] = 0.f;
    for (int ci = 0; ci < 64; ++ci) {
        __syncthreads();
        for (int idx = tid; idx < 3 * 3 * 7 * 114; idx += 256) {
            int c = idx % 114, rest = idx / 114;
            int ho = rest % 7; rest /= 7;
            int kh = rest % 3, kd = rest / 3;
            int r = 8 * (hb * 7 + ho) + h + kh - 7;
            int d = t + kd - 1, colx = c - 7;
            float v = 0.f;
            if (r >= 0 && d >= 0 && d < 16 && colx >= 0)
                v = xin[(((size_t)(b * 64 + ci) * 16 + d) * 112 + r) * 112 + colx];
            Xl[((kd * 3 + kh) * 7 + ho) * XL_ROWSTRIDE + c] = v;
        }
        for (int idx = tid; idx < 8 * 16 * 27; idx += 256) {
            int k2 = idx % 27, rest = idx / 27;
            int co_l = rest % 16, wi = rest / 16;
            Wl[wi * WL_WSTRIDE + co_l * 27 + k2] =
                wt[(((size_t)(h * 8 + wi) * 64 + (ct * 16 + co_l)) * 64 + ci) * 27 + k2];
        }
        __syncthreads();
#pragma unroll
        for (int kd = 0; kd < 3; ++kd)
#pragma unroll
            for (int kh = 0; kh < 3; ++kh)
#pragma unroll
                for (int kw = 0; kw < 3; ++kw) {
                    const int k2 = (kd * 3 + kh) * 3 + kw;
                    float xv[7];
#pragma unroll
                    for (int ho = 0; ho < 7; ++ho)
                        xv[ho] = Xl[((kd * 3 + kh) * 7 + ho) * XL_ROWSTRIDE + xr + kw];
                    float wv[8];
#pragma unroll
                    for (int c = 0; c < 8; ++c)
                        wv[c] = Wl[wq * WL_WSTRIDE + (cg * 8 + c) * 27 + k2];
#pragma unroll
                    for (int c = 0; c < 8; ++c)
#pragma unroll
                        for (int ho = 0; ho < 7; ++ho)
                            acc[c][ho] += wv[c] * xv[ho];
                }
    }
    if (xl < 112) {
#pragma unroll
        for (int c = 0; c < 8; ++c) {
            const int co = ct * 16 + cg * 8 + c;
            const float bv = bs[(h * 8 + wq) * 64 + co];
#pragma unroll
            for (int ho = 0; ho < 7; ++ho) {
                const int y = 8 * (hb * 7 + ho) + h;
                out[(((size_t)(b * 64 + co) * 16 + t) * 112 + y) * 112 + xl] = acc[c][ho] + bv;
            }
        }
    }
}

extern "C" void kernel_launch(void* const* d_in, const int* in_sizes, int n_in,
                              void* d_out, int out_size, void* d_ws, size_t ws_size,
                              hipStream_t stream) {
    const float* x  = (const float*)d_in[0];
    const float* wg = (const float*)d_in[1];
    const float* bi = (const float*)d_in[2];
    float* out = (float*)d_out;
    if (ws_size >= WPP_BYTES + XPP_BYTES) {
        __hip_bfloat16* wpp = (__hip_bfloat16*)d_ws;
        __hip_bfloat16* xpp = (__hip_bfloat16*)((char*)d_ws + WPP_BYTES);
        prep<<<1024, 512, 114688, stream>>>(x, wg, xpp, wpp);
        patgemm<<<1792, 256, 0, stream>>>(xpp, (const char*)wpp, bi, out);
    } else {
        patconv3d_fp32<<<2048, 256, 0, stream>>>(x, wg, bi, out);
    }
}

// Round 12
// 256.660 us; speedup vs baseline: 1.4799x; 1.4799x over previous
//
#include <hip/hip_runtime.h>
#include <hip/hip_bf16.h>
#include <stdint.h>

typedef __attribute__((ext_vector_type(8))) short short8;
typedef __attribute__((ext_vector_type(4))) float f32x4;

#define WPP_BYTES 14155776ull   // 64hw*27tap*64co*64ci*2B (first in ws)
#define XPP_BYTES 66355200ull   // 8rh*8cw*2b*15rho*15cwo*18d*64ci*2B

__device__ __forceinline__ void gl2lds16(const void* g, void* l) {
    __builtin_amdgcn_global_load_lds(
        (const __attribute__((address_space(1))) unsigned int*)g,
        (__attribute__((address_space(3))) unsigned int*)l, 16, 0, 0);
}

// ---------------- bzero: zero only X''' halo (rho=0 | cwo=0 | d in {0,17}) --
__global__ __launch_bounds__(256)
void bzero(uint4* __restrict__ xpp) {
    const uint4 z = {0u, 0u, 0u, 0u};
    const int total = 935936;
    for (int idx = blockIdx.x * 256 + threadIdx.x; idx < total;
         idx += gridDim.x * 256) {
        int u;
        if (idx < 276480) {
            int slab = idx / 2160, off = idx % 2160;
            u = slab * 32400 + off;
        } else if (idx < 534528) {
            int k = idx - 276480;
            int run = k / 144, off = k % 144;
            int slab = run / 14, rho = run % 14 + 1;
            u = slab * 32400 + rho * 2160 + off;
        } else {
            int k = idx - 534528;
            int run = k / 8, off = k % 8;
            int slab = run / 392, r2 = run % 392;
            int rho = r2 / 28 + 1, r3 = r2 % 28;
            int cwo = r3 / 2 + 1, d = (r3 & 1) * 17;
            u = slab * 32400 + rho * 2160 + cwo * 144 + d * 8 + off;
        }
        xpp[u] = z;
    }
}

// ---------------- T1: X (f32) -> X''' (bf16, space-to-depth, d-innermost) --
__global__ __launch_bounds__(512)
void xform_x(const float* __restrict__ xin, __hip_bfloat16* __restrict__ xpp) {
    extern __shared__ __hip_bfloat16 Xl[];
    const int bid = blockIdx.x;
    const int rho = bid % 14, d = (bid / 14) % 16, b = bid / 224;
    const int tid = threadIdx.x;
    for (int f = tid; f < 64 * 8 * 28; f += 512) {
        int ci = f / 224, rem = f % 224;
        int r = rem / 28, c4 = (rem % 28) * 4;
        const float4 v = *(const float4*)&xin[
            ((((size_t)b * 64 + ci) * 16 + d) * 112 + (rho * 8 + r)) * 112 + c4];
        const float vv[4] = {v.x, v.y, v.z, v.w};
#pragma unroll
        for (int u = 0; u < 4; ++u) {
            int c = c4 + u;
            Xl[(r * 112 + c) * 64 + (ci ^ ((c & 7) << 3))] = __float2bfloat16(vv[u]);
        }
    }
    __syncthreads();
    for (int f = tid; f < 896 * 8; f += 512) {
        int pos = f >> 3, j = f & 7;
        int r = pos / 112, c = pos % 112;
        int cw = c & 7, cwo = c >> 3;
        uint4 v = *(const uint4*)&Xl[pos * 64 + ((j * 8) ^ ((c & 7) << 3))];
        size_t dst = (((((size_t)(r * 8 + cw) * 2 + b) * 15 + (rho + 1)) * 15
                       + (cwo + 1)) * 18 + (d + 1)) * 64 + j * 8;
        *(uint4*)(xpp + dst) = v;
    }
}

// ---------------- T2: W (f32) -> W''[hw][tap][co64][cic8x16B] (bf16) -------
__global__ __launch_bounds__(256)
void xform_w(const float* __restrict__ wt, __hip_bfloat16* __restrict__ wpp) {
    __shared__ __hip_bfloat16 lw[8 * 27 * 72];
    const int hw = blockIdx.x >> 3, cc = blockIdx.x & 7;
    for (int f = threadIdx.x; f < 8 * 64 * 27; f += 256) {
        int k = f % 27, ci = (f / 27) % 64, co = f / (27 * 64);
        float v = wt[(size_t)hw * 110592 + (size_t)(cc * 8 + co) * 1728 + ci * 27 + k];
        lw[(co * 27 + k) * 72 + ci] = __float2bfloat16(v);
    }
    __syncthreads();
    for (int f = threadIdx.x; f < 27 * 8 * 8; f += 256) {
        int cic = f % 8, co = (f / 8) % 8, k = f / 64;
        uint4 v = *(const uint4*)&lw[(co * 27 + k) * 72 + cic * 8];
        size_t dst = (((size_t)hw * 27 + k) * 64 + (cc * 8 + co)) * 64 + cic * 8;
        *(uint4*)(wpp + dst) = v;
    }
}

// ---------------- GEMM: per (h,w,b,mc): [224m x 64co], m=(wo14,t16) --------
// MEASURED-BEST (r10): 256 thr / 4 waves (mg2 x ng2), wave = 7 m x 2 n tiles.
// 9 round-pairs p=(kh,kw); A staged ONCE per p as full-18d line halves
// (16128 B used, buf padded to 16384 — gl2lds dst is base+lane*16 linear,
// tail lands in pad); taps for line p are {p, p+9, p+18}; B staged ONCE per
// tap to ring-6 [p&1][kd] x 8 KB, one pair ahead. LDS 81920 B = 2 blk/CU.
// Simple sync: stage -> compute -> __syncthreads. Conflicts measured 0.
// Structural plateau: 8 variants (bytes/TLP/sync/MFMA-shape) all 207-326 us;
// more TLP thrashes L2 (r11), counted vmcnt neutral (r5/r6), 32x32 worse (r7).

__global__ __launch_bounds__(256, 2)
void patgemm(const __hip_bfloat16* __restrict__ xpp,
             const char* __restrict__ wppc,
             const float* __restrict__ bs,
             float* __restrict__ out) {
    extern __shared__ char smem[];  // A: 2 x 16384 (16128 used) | B: 6 x 8192
    const char* xppc = (const char*)xpp;
    const int bid = blockIdx.x;
    const int h = bid & 7, w = (bid >> 3) & 7, b = (bid >> 6) & 1, mc = bid >> 7;
    const int hw = h * 8 + w;
    const int tid = threadIdx.x, wv = tid >> 6;
    const int lane = tid & 63, col = lane & 15, quad = lane >> 4;
    const int mg = wv >> 1, ng = wv & 1;

    uint32_t aoff[4];
#pragma unroll
    for (int i = 0; i < 4; ++i) {
        int u = tid + i * 256; if (u > 1007) u = 1007;   // src clamp only
        int wo = u / 72, rem = u - wo * 72;
        int d = rem >> 2, qp = rem & 3, q = qp ^ ((d >> 1) & 3);
        aoff[i] = (uint32_t)(wo * 2304 + d * 128 + q * 16);
    }
    uint32_t boff[2];
#pragma unroll
    for (int i = 0; i < 2; ++i) {
        int u = tid + i * 256;
        boff[i] = (uint32_t)((u >> 3) * 128 + (((u & 7) ^ ((u >> 3) & 7)) << 4));
    }
    uint32_t rofs[3];
#pragma unroll
    for (int kd = 0; kd < 3; ++kd) {
        int d = col + kd;
        rofs[kd] = (uint32_t)(d * 64 + ((quad ^ ((d >> 1) & 3)) << 4));
    }
    uint32_t bofsw[2];
#pragma unroll
    for (int hf = 0; hf < 2; ++hf)
        bofsw[hf] = (uint32_t)(col * 128 + (((hf * 4 + quad) ^ (col & 7)) << 4));

    f32x4 acc[7][2];
#pragma unroll
    for (int j = 0; j < 7; ++j)
#pragma unroll
        for (int n = 0; n < 2; ++n) acc[j][n] = (f32x4){0.f, 0.f, 0.f, 0.f};

    const char* wbase = wppc + (size_t)hw * 221184;

    auto lineBase = [&](int p) -> const char* {
        const int kh = (p >= 6) ? 2 : (p >= 3 ? 1 : 0);
        const int kw = p - 3 * kh;
        const int r0 = h + kh - 7, c0 = w + kw - 7;
        return xppc + (size_t)(((((r0 & 7) * 8 + (c0 & 7)) * 2 + b) * 15
                    + ((r0 >> 3) + 1 + mc)) * 15 + ((c0 >> 3) + 1)) * 2304;
    };
    auto STGA = [&](const char* lb, int hf, int buf) {
#pragma unroll
        for (int i = 0; i < 4; ++i)
            gl2lds16(lb + aoff[i] + hf * 64,
                     smem + buf * 16384 + (tid + i * 256) * 16);
    };
    auto STGB = [&](int tap, int slot) {
#pragma unroll
        for (int i = 0; i < 2; ++i)
            gl2lds16(wbase + (size_t)tap * 8192 + boff[i],
                     smem + 32768 + slot * 8192 + (tid + i * 256) * 16);
    };

    // prologue: A(p=0,hf0)->buf0; B taps {0,9,18} (kd=0,1,2) -> slots 0,1,2
    const char* lb = lineBase(0);
    STGA(lb, 0, 0);
    STGB(0, 0); STGB(9, 1); STGB(18, 2);
    __syncthreads();

#pragma unroll 1
    for (int p = 0; p < 9; ++p) {
        const int pp = p & 1;
        STGA(lb, 1, 1);                       // same line, other ci-half
        if (p < 8) {                          // taps for line p+1: {p+1+9kd}
            const int sb = (1 - pp) * 3;
            STGB(p + 1, sb); STGB(p + 10, sb + 1); STGB(p + 19, sb + 2);
        }
#pragma unroll
        for (int kd = 0; kd < 3; ++kd) {
            const char* Bb = smem + 32768 + (pp * 3 + kd) * 8192;
            short8 bf0 = *(const short8*)(Bb + (ng * 2 + 0) * 2048 + bofsw[0]);
            short8 bf1 = *(const short8*)(Bb + (ng * 2 + 1) * 2048 + bofsw[0]);
#pragma unroll
            for (int j = 0; j < 7; ++j) {
                short8 af = *(const short8*)(smem + (mg * 7 + j) * 1152 + rofs[kd]);
                acc[j][0] = __builtin_amdgcn_mfma_f32_16x16x32_bf16(af, bf0, acc[j][0], 0, 0, 0);
                acc[j][1] = __builtin_amdgcn_mfma_f32_16x16x32_bf16(af, bf1, acc[j][1], 0, 0, 0);
            }
        }
        __syncthreads();
        if (p < 8) { lb = lineBase(p + 1); STGA(lb, 0, 0); }
#pragma unroll
        for (int kd = 0; kd < 3; ++kd) {
            const char* Bb = smem + 32768 + (pp * 3 + kd) * 8192;
            short8 bf0 = *(const short8*)(Bb + (ng * 2 + 0) * 2048 + bofsw[1]);
            short8 bf1 = *(const short8*)(Bb + (ng * 2 + 1) * 2048 + bofsw[1]);
#pragma unroll
            for (int j = 0; j < 7; ++j) {
                short8 af = *(const short8*)(smem + 16384 + (mg * 7 + j) * 1152 + rofs[kd]);
                acc[j][0] = __builtin_amdgcn_mfma_f32_16x16x32_bf16(af, bf0, acc[j][0], 0, 0, 0);
                acc[j][1] = __builtin_amdgcn_mfma_f32_16x16x32_bf16(af, bf1, acc[j][1], 0, 0, 0);
            }
        }
        __syncthreads();
    }

    // epilogue: co = (ng*2+n)*16+col, t = quad*4+jj, wo = mg*7+j
    const float* bsl = bs + hw * 64;
    const int y = 8 * mc + h;
#pragma unroll
    for (int j = 0; j < 7; ++j) {
        const int x = 8 * (mg * 7 + j) + w;
#pragma unroll
        for (int n = 0; n < 2; ++n) {
            const int co = (ng * 2 + n) * 16 + col;
            const float bv = bsl[co];
#pragma unroll
            for (int jj = 0; jj < 4; ++jj) {
                const int t = quad * 4 + jj;
                out[((((size_t)b * 64 + co) * 16 + t) * 112 + y) * 112 + x]
                    = acc[j][n][jj] + bv;
            }
        }
    }
}

// ---------------- fallback: round-1 fp32 kernel (used if ws too small) -----
#define XL_ROWSTRIDE 116
#define WL_WSTRIDE (17*27)

__global__ __launch_bounds__(256, 3)
void patconv3d_fp32(const float* __restrict__ xin,
                    const float* __restrict__ wt,
                    const float* __restrict__ bs,
                    float* __restrict__ out) {
    __shared__ float Xl[3*3*7*XL_ROWSTRIDE];
    __shared__ float Wl[8*WL_WSTRIDE];
    const int bid = blockIdx.x;
    const int ct = bid & 3, hb = (bid >> 2) & 1, h = (bid >> 3) & 7;
    const int t = (bid >> 6) & 15, b = (bid >> 10) & 1;
    const int tid = threadIdx.x;
    const int xl = tid & 127, cg = tid >> 7;
    const int xr = (xl < 112) ? xl : 111;
    const int wq = xl & 7;
    float acc[8][7];
#pragma unroll
    for (int c = 0; c < 8; ++c)
#pragma unroll
        for (int ho = 0; ho < 7; ++ho) acc[c][ho] = 0.f;
    for (int ci = 0; ci < 64; ++ci) {
        __syncthreads();
        for (int idx = tid; idx < 3 * 3 * 7 * 114; idx += 256) {
            int c = idx % 114, rest = idx / 114;
            int ho = rest % 7; rest /= 7;
            int kh = rest % 3, kd = rest / 3;
            int r = 8 * (hb * 7 + ho) + h + kh - 7;
            int d = t + kd - 1, colx = c - 7;
            float v = 0.f;
            if (r >= 0 && d >= 0 && d < 16 && colx >= 0)
                v = xin[(((size_t)(b * 64 + ci) * 16 + d) * 112 + r) * 112 + colx];
            Xl[((kd * 3 + kh) * 7 + ho) * XL_ROWSTRIDE + c] = v;
        }
        for (int idx = tid; idx < 8 * 16 * 27; idx += 256) {
            int k2 = idx % 27, rest = idx / 27;
            int co_l = rest % 16, wi = rest / 16;
            Wl[wi * WL_WSTRIDE + co_l * 27 + k2] =
                wt[(((size_t)(h * 8 + wi) * 64 + (ct * 16 + co_l)) * 64 + ci) * 27 + k2];
        }
        __syncthreads();
#pragma unroll
        for (int kd = 0; kd < 3; ++kd)
#pragma unroll
            for (int kh = 0; kh < 3; ++kh)
#pragma unroll
                for (int kw = 0; kw < 3; ++kw) {
                    const int k2 = (kd * 3 + kh) * 3 + kw;
                    float xv[7];
#pragma unroll
                    for (int ho = 0; ho < 7; ++ho)
                        xv[ho] = Xl[((kd * 3 + kh) * 7 + ho) * XL_ROWSTRIDE + xr + kw];
                    float wv[8];
#pragma unroll
                    for (int c = 0; c < 8; ++c)
                        wv[c] = Wl[wq * WL_WSTRIDE + (cg * 8 + c) * 27 + k2];
#pragma unroll
                    for (int c = 0; c < 8; ++c)
#pragma unroll
                        for (int ho = 0; ho < 7; ++ho)
                            acc[c][ho] += wv[c] * xv[ho];
                }
    }
    if (xl < 112) {
#pragma unroll
        for (int c = 0; c < 8; ++c) {
            const int co = ct * 16 + cg * 8 + c;
            const float bv = bs[(h * 8 + wq) * 64 + co];
#pragma unroll
            for (int ho = 0; ho < 7; ++ho) {
                const int y = 8 * (hb * 7 + ho) + h;
                out[(((size_t)(b * 64 + co) * 16 + t) * 112 + y) * 112 + xl] = acc[c][ho] + bv;
            }
        }
    }
}

extern "C" void kernel_launch(void* const* d_in, const int* in_sizes, int n_in,
                              void* d_out, int out_size, void* d_ws, size_t ws_size,
                              hipStream_t stream) {
    const float* x  = (const float*)d_in[0];
    const float* wg = (const float*)d_in[1];
    const float* bi = (const float*)d_in[2];
    float* out = (float*)d_out;
    if (ws_size >= WPP_BYTES + XPP_BYTES) {
        __hip_bfloat16* wpp = (__hip_bfloat16*)d_ws;
        __hip_bfloat16* xpp = (__hip_bfloat16*)((char*)d_ws + WPP_BYTES);
        bzero<<<1024, 256, 0, stream>>>((uint4*)xpp);
        xform_x<<<448, 512, 114688, stream>>>(x, xpp);
        xform_w<<<512, 256, 0, stream>>>(wg, wpp);
        patgemm<<<1792, 256, 81920, stream>>>(xpp, (const char*)wpp, bi, out);
    } else {
        patconv3d_fp32<<<2048, 256, 0, stream>>>(x, wg, bi, out);
    }
}